// Round 8
// baseline (131.744 us; speedup 1.0000x reference)
//
#include <hip/hip_runtime.h>
#include <stddef.h>

// Problem constants (fixed by setup_inputs)
constexpr int B = 32;
constexpr int T = 2048;
constexpr int F = 512;   // K
constexpr int U = 128;   // N
constexpr float NEG_BIG = -1.0e9f;

typedef __attribute__((ext_vector_type(8))) short short8;   // MFMA A/B frag (8 bf16)
typedef __attribute__((ext_vector_type(4))) float f32x4;    // MFMA C/D frag / NT store

__device__ __forceinline__ unsigned short f2bf(float f) {
    unsigned int u = __float_as_uint(f);
    u += 0x7FFFu + ((u >> 16) & 1u);     // round-to-nearest-even
    return (unsigned short)(u >> 16);
}
__device__ __forceinline__ float bf2f(unsigned short h) {
    return __uint_as_float(((unsigned int)h) << 16);
}

// ---------------------------------------------------------------------------
// Prep: W1 [F,U] fp32 -> transposed split-bf16 W1T_hi/lo [U,F]. Tiny.
// ---------------------------------------------------------------------------
__global__ __launch_bounds__(256) void prep_w(
    const float* __restrict__ W1,
    unsigned short* __restrict__ WThi,
    unsigned short* __restrict__ WTlo)
{
    const int idx = blockIdx.x * 256 + threadIdx.x;   // 0..65535
    const int k = idx >> 7;          // F row
    const int u = idx & 127;         // U col
    const float w = W1[idx];
    const unsigned short hi = f2bf(w);
    const unsigned short lo = f2bf(w - bf2f(hi));
    WThi[(size_t)u * F + k] = hi;
    WTlo[(size_t)u * F + k] = lo;
}

// ---------------------------------------------------------------------------
// Pass 1: scores via split-bf16 MFMA.
// 256 threads = 4 waves; each wave owns 32 frames (2 m-frags) x all 128 u.
// -> B-fragment LDS reads amortize over 2x M vs the 16-frame design:
//    per-CU ds_read_b128 ~2048 (10 us) < per-CU x HBM stream (21 us).
// W (hi/lo) staged in LDS in 4 phases of QK=128 k (67.6 KB -> 2 blocks/CU).
// LDS row stride LDK=132 elems: bank(l15,g) = (2*l15+4g+16s) mod 32 ->
// uniform 8 words/bank per b128 wave-read, conflict-free.
// A (x): depth-2 k-step REGISTER RING - before computing k-step s, issue
// loads for k+64 into the just-consumed slot; >=2 k-steps of MFMA+ds_read
// (~600cy) always cover load latency, including across the stage barrier.
// acc += x_hi*W_hi + x_hi*W_lo + x_lo*W_hi  (split-bf16, fp32 accumulate;
// selection-exact vs fp32 reference, absmax 0.0 in R2-R7).
// ---------------------------------------------------------------------------
constexpr int QK  = 128;  // k per stage phase
constexpr int LDK = 132;  // LDS row stride in bf16 elems

__global__ __launch_bounds__(256) void score_kernel(
    const float* __restrict__ x,            // [B*T, F]
    const unsigned short* __restrict__ WThi,// [U, F] bf16 bits
    const unsigned short* __restrict__ WTlo,// [U, F]
    const float* __restrict__ b1,           // [U]
    const float* __restrict__ W2,           // [U]
    const float* __restrict__ b2,           // [1]
    float* __restrict__ scores)             // [B*T]
{
    __shared__ __align__(16) unsigned short wh[U * LDK];   // 33792 B
    __shared__ __align__(16) unsigned short wl[U * LDK];   // 33792 B

    const int tid  = threadIdx.x;
    const int wid  = tid >> 6;                  // 0..3
    const int lane = tid & 63;
    const int l15  = lane & 15;
    const int g    = lane >> 4;                 // k-group within wave
    const int wm0  = blockIdx.x * 128 + wid * 32;  // wave's first frame

    const float* xr0 = x + (size_t)(wm0 + l15) * F + g * 8;        // m-frag 0
    const float* xr1 = xr0 + (size_t)16 * F;                       // m-frag 1

    // stage mapping: thread pair -> u-row; each thread: 8 short8 chunks/array
    const int sr = tid >> 1;                    // u-row 0..127
    const int sc = (tid & 1) * 8;               // first chunk (of 16 per row)
    const unsigned short* WHrow = WThi + (size_t)sr * F;
    const unsigned short* WLrow = WTlo + (size_t)sr * F;

    f32x4 acc[2][8] = {};       // [m-frag][n-frag], fp32
    bool nz0 = false, nz1 = false;

    // depth-2 ring: slot s&1 holds k-step s's x (2 float4 per m-frag)
    float4 p0a[2], p0b[2], p1a[2], p1b[2];
#define ISSUE(slot, kk)                                                    \
    do {                                                                   \
        p0a[slot] = *reinterpret_cast<const float4*>(xr0 + (kk));          \
        p0b[slot] = *reinterpret_cast<const float4*>(xr0 + (kk) + 4);      \
        p1a[slot] = *reinterpret_cast<const float4*>(xr1 + (kk));          \
        p1b[slot] = *reinterpret_cast<const float4*>(xr1 + (kk) + 4);      \
    } while (0)

    ISSUE(0, 0);
    ISSUE(1, 32);

    for (int p = 0; p < F / QK; ++p) {
        const int kbase = p * QK;

        // ---- stage W chunk: 128 u-rows x 128 k (hi & lo), 64 KB ----
#pragma unroll
        for (int c = 0; c < 8; ++c) {
            const int off = (sc + c) * 8;
            *reinterpret_cast<short8*>(&wh[sr * LDK + off]) =
                *reinterpret_cast<const short8*>(&WHrow[kbase + off]);
            *reinterpret_cast<short8*>(&wl[sr * LDK + off]) =
                *reinterpret_cast<const short8*>(&WLrow[kbase + off]);
        }
        __syncthreads();

        // ---- compute 4 k32-steps; ring-prefetch x two steps ahead ----
#pragma unroll
        for (int s = 0; s < 4; ++s) {
            const int slot = s & 1;
            const float4 a0 = p0a[slot], b0 = p0b[slot];
            const float4 a1 = p1a[slot], b1f = p1b[slot];

            const int kk = kbase + s * 32 + 64;      // two steps ahead
            if (kk < F) ISSUE(slot, kk);

            const float av0[8] = { a0.x, a0.y, a0.z, a0.w, b0.x, b0.y, b0.z, b0.w };
            const float av1[8] = { a1.x, a1.y, a1.z, a1.w, b1f.x, b1f.y, b1f.z, b1f.w };
            short8 ah0, al0, ah1, al1;
#pragma unroll
            for (int j = 0; j < 8; ++j) {
                unsigned short hi = f2bf(av0[j]);
                ah0[j] = (short)hi;
                al0[j] = (short)f2bf(av0[j] - bf2f(hi));
                nz0 |= (av0[j] != 0.0f);
                hi = f2bf(av1[j]);
                ah1[j] = (short)hi;
                al1[j] = (short)f2bf(av1[j] - bf2f(hi));
                nz1 |= (av1[j] != 0.0f);
            }
            const int kloc = s * 32 + g * 8;
#pragma unroll
            for (int nf = 0; nf < 8; ++nf) {
                const int ub = (nf * 16 + l15) * LDK + kloc;
                const short8 bh = *reinterpret_cast<const short8*>(&wh[ub]);
                const short8 bl = *reinterpret_cast<const short8*>(&wl[ub]);
                acc[0][nf] = __builtin_amdgcn_mfma_f32_16x16x32_bf16(ah0, bh, acc[0][nf], 0, 0, 0);
                acc[0][nf] = __builtin_amdgcn_mfma_f32_16x16x32_bf16(ah0, bl, acc[0][nf], 0, 0, 0);
                acc[0][nf] = __builtin_amdgcn_mfma_f32_16x16x32_bf16(al0, bh, acc[0][nf], 0, 0, 0);
                acc[1][nf] = __builtin_amdgcn_mfma_f32_16x16x32_bf16(ah1, bh, acc[1][nf], 0, 0, 0);
                acc[1][nf] = __builtin_amdgcn_mfma_f32_16x16x32_bf16(ah1, bl, acc[1][nf], 0, 0, 0);
                acc[1][nf] = __builtin_amdgcn_mfma_f32_16x16x32_bf16(al1, bh, acc[1][nf], 0, 0, 0);
            }
        }
        __syncthreads();
    }
#undef ISSUE

    // per-m-frag nz ballots: frame f (l15=f) nonzero iff any of the 4 g-lanes
    const unsigned long long nzb0 = __ballot(nz0);
    const unsigned long long nzb1 = __ballot(nz1);

    // epilogue constants for this lane's 8 u-columns
    float b1v[8], w2v[8];
#pragma unroll
    for (int nf = 0; nf < 8; ++nf) {
        const int u = nf * 16 + l15;
        b1v[nf] = b1[u];
        w2v[nf] = W2[u];
    }
    const float bias2 = b2[0];

    // C/D layout (HW-verified): col = lane&15, row = (lane>>4)*4 + reg.
#pragma unroll
    for (int mf = 0; mf < 2; ++mf) {
        const unsigned long long nzb = mf ? nzb1 : nzb0;
#pragma unroll
        for (int r = 0; r < 4; ++r) {
            float s = 0.0f;
#pragma unroll
            for (int nf = 0; nf < 8; ++nf) {
                float h = acc[mf][nf][r] + b1v[nf];
                h = h > 0.0f ? h : 0.0f;
                s += h * w2v[nf];
            }
            s += __shfl_xor(s, 1);
            s += __shfl_xor(s, 2);
            s += __shfl_xor(s, 4);
            s += __shfl_xor(s, 8);
            if (l15 == 0) {
                const int fr = g * 4 + r;        // row within m-frag
                const bool nz = (nzb & (0x0001000100010001ULL << fr)) != 0ULL;
                scores[wm0 + mf * 16 + fr] = nz ? (s + bias2) : NEG_BIG;
            }
        }
    }
}

// ---------------------------------------------------------------------------
// Pass 2: per batch row, sel[t] = 1 iff frame t in top-k (stable rank-by-
// count, matching lax.top_k's lower-index-first tie handling).
// ---------------------------------------------------------------------------
__global__ __launch_bounds__(256) void topk_kernel(
    const float* __restrict__ scores,  // [B*T]
    const int* __restrict__ kp,        // [1]
    int* __restrict__ sel)             // [B*T]
{
    __shared__ float srow[T];

    const int b     = blockIdx.x >> 3;   // 8 chunks of 256 frames per row
    const int chunk = blockIdx.x & 7;
    const float* row = scores + (size_t)b * T;

    for (int i = threadIdx.x; i < T / 4; i += 256)
        reinterpret_cast<float4*>(srow)[i] =
            reinterpret_cast<const float4*>(row)[i];
    __syncthreads();

    const int t   = chunk * 256 + threadIdx.x;
    const float s = srow[t];
    int cnt = 0;
    for (int i = 0; i < T / 4; ++i) {
        const float4 v = reinterpret_cast<const float4*>(srow)[i];
        const int base = i * 4;
        cnt += (v.x > s) || (v.x == s && (base + 0) < t);
        cnt += (v.y > s) || (v.y == s && (base + 1) < t);
        cnt += (v.z > s) || (v.z == s && (base + 2) < t);
        cnt += (v.w > s) || (v.w == s && (base + 3) < t);
    }
    sel[(size_t)b * T + t] = (cnt < kp[0]) ? 1 : 0;
}

// ---------------------------------------------------------------------------
// Pass 3: out[m,:] = sel[m] ? x[m,:] : 0.
// One block per 32 frames (2048 blocks -> 8 blocks/CU). Non-temporal stores
// (output never re-read): stream at fill rate, don't evict x from L3.
// ---------------------------------------------------------------------------
__global__ __launch_bounds__(256) void out_kernel(
    const float* __restrict__ x,
    const int* __restrict__ sel,
    float* __restrict__ out)
{
    __shared__ int ssel[32];

    const int fbase = blockIdx.x * 32;
    if (threadIdx.x < 32) ssel[threadIdx.x] = sel[fbase + threadIdx.x];
    __syncthreads();

    const size_t base4 = (size_t)fbase * (F / 4);
    const f32x4* x4 = reinterpret_cast<const f32x4*>(x) + base4;
    f32x4*       o4 = reinterpret_cast<f32x4*>(out) + base4;
    const f32x4 z = {0.0f, 0.0f, 0.0f, 0.0f};

#pragma unroll
    for (int it = 0; it < 16; ++it) {
        const int q  = it * 256 + threadIdx.x;
        const int fr = q >> 7;               // frame within 32 (F/4 = 128)
        f32x4 v = z;
        if (ssel[fr]) v = x4[q];
        __builtin_nontemporal_store(v, &o4[q]);
    }
}

// ---------------------------------------------------------------------------
extern "C" void kernel_launch(void* const* d_in, const int* in_sizes, int n_in,
                              void* d_out, int out_size, void* d_ws, size_t ws_size,
                              hipStream_t stream)
{
    const float* x  = (const float*)d_in[0];
    const float* W1 = (const float*)d_in[1];
    const float* b1 = (const float*)d_in[2];
    const float* W2 = (const float*)d_in[3];
    const float* b2 = (const float*)d_in[4];
    const int*   kp = (const int*)d_in[5];

    char* ws = (char*)d_ws;
    unsigned short* WThi = (unsigned short*)ws;               // 131072 B
    unsigned short* WTlo = (unsigned short*)(ws + 131072);    // 131072 B
    float* scores        = (float*)(ws + 262144);             // 262144 B
    int*   sel           = (int*)(ws + 524288);               // 262144 B

    float* out = (float*)d_out;

    prep_w<<<256, 256, 0, stream>>>(W1, WThi, WTlo);
    score_kernel<<<(B * T) / 128, 256, 0, stream>>>(x, WThi, WTlo, b1, W2, b2, scores);
    topk_kernel<<<B * 8, 256, 0, stream>>>(scores, kp, sel);
    out_kernel<<<(B * T) / 32, 256, 0, stream>>>(x, sel, out);
}

// Round 9
// 128.994 us; speedup vs baseline: 1.0213x; 1.0213x over previous
//
#include <hip/hip_runtime.h>
#include <stddef.h>

// Problem constants (fixed by setup_inputs)
constexpr int B = 32;
constexpr int T = 2048;
constexpr int F = 512;   // K
constexpr int U = 128;   // N
constexpr float NEG_BIG = -1.0e9f;

typedef __attribute__((ext_vector_type(8))) short short8;   // MFMA A/B frag (8 bf16)
typedef __attribute__((ext_vector_type(4))) float f32x4;    // MFMA C/D frag / NT store

__device__ __forceinline__ unsigned short f2bf(float f) {
    unsigned int u = __float_as_uint(f);
    u += 0x7FFFu + ((u >> 16) & 1u);     // round-to-nearest-even
    return (unsigned short)(u >> 16);
}
__device__ __forceinline__ float bf2f(unsigned short h) {
    return __uint_as_float(((unsigned int)h) << 16);
}

// ---------------------------------------------------------------------------
// Prep: W1 [F,U] fp32 -> transposed split-bf16 W1T_hi/lo [U,F]. Tiny.
// ---------------------------------------------------------------------------
__global__ __launch_bounds__(256) void prep_w(
    const float* __restrict__ W1,
    unsigned short* __restrict__ WThi,
    unsigned short* __restrict__ WTlo)
{
    const int idx = blockIdx.x * 256 + threadIdx.x;   // 0..65535
    const int k = idx >> 7;          // F row
    const int u = idx & 127;         // U col
    const float w = W1[idx];
    const unsigned short hi = f2bf(w);
    const unsigned short lo = f2bf(w - bf2f(hi));
    WThi[(size_t)u * F + k] = hi;
    WTlo[(size_t)u * F + k] = lo;
}

// ---------------------------------------------------------------------------
// Pass 1: scores via split-bf16 MFMA — the R4 structure VERBATIM (the fastest
// measured score config, ~48 us by cross-round arithmetic: R4 total 129.7 -
// topk_out 78.3 - prep ~3). 512 threads = 8 waves; each wave owns 16 frames
// x all 128 u; 128 frames/block, 512 blocks, 2 blocks/CU (67.6 KB LDS),
// 16 waves/CU. B (W1T hi/lo) staged in LDS in 4 quarter-K phases (QK=128,
// 8 barriers total). LDS row stride LDK=132 elems = 66 words === 2 (mod 32):
// 16-row x 4-group ds_read_b128 covers all 32 banks uniformly, conflict-free.
// A (x): direct coalesced global loads inside the k-step (no prefetch — the
// R5/R7/R8 prefetch variants all regressed score to ~100 us, likely VGPR
// pressure; empirics over theory).
// acc += x_hi*W_hi + x_hi*W_lo + x_lo*W_hi  (split-bf16, fp32 accumulate;
// selection-exact vs fp32 reference, absmax 0.0 in R2-R8).
// ---------------------------------------------------------------------------
constexpr int QK  = 128;   // k per stage phase
constexpr int LDK = 132;   // LDS row stride in bf16 elems

__global__ __launch_bounds__(512, 4) void score_kernel(
    const float* __restrict__ x,            // [B*T, F]
    const unsigned short* __restrict__ WThi,// [U, F] bf16 bits
    const unsigned short* __restrict__ WTlo,// [U, F]
    const float* __restrict__ b1,           // [U]
    const float* __restrict__ W2,           // [U]
    const float* __restrict__ b2,           // [1]
    float* __restrict__ scores)             // [B*T]
{
    __shared__ __align__(16) unsigned short wh[U * LDK];   // 33792 B
    __shared__ __align__(16) unsigned short wl[U * LDK];   // 33792 B

    const int tid  = threadIdx.x;
    const int wid  = tid >> 6;                  // 0..7
    const int lane = tid & 63;
    const int l15  = lane & 15;
    const int g    = lane >> 4;                 // k-group within wave
    const int m0   = blockIdx.x * 128 + wid * 16;

    const float* xrow = x + (size_t)(m0 + l15) * F + g * 8;

    // stage mapping: thread -> (row, 64B column group)
    const int sr = tid >> 2;                    // u-row 0..127
    const int sc = tid & 3;

    f32x4 acc[8] = {};          // 8 n-frags (u = nf*16 + l15), fp32
    bool nzflag = false;

    for (int q = 0; q < 4; ++q) {
        const int kbase = q * QK;

        // ---- stage W quarter: 128 u-rows x 128 k (hi & lo), 64 KB ----
#pragma unroll
        for (int it = 0; it < 4; ++it) {
            const int off = (sc + 4 * it) * 8;
            *reinterpret_cast<short8*>(&wh[sr * LDK + off]) =
                *reinterpret_cast<const short8*>(&WThi[(size_t)sr * F + kbase + off]);
            *reinterpret_cast<short8*>(&wl[sr * LDK + off]) =
                *reinterpret_cast<const short8*>(&WTlo[(size_t)sr * F + kbase + off]);
        }
        __syncthreads();

        // ---- compute 4 k32-steps from LDS ----
#pragma unroll
        for (int s = 0; s < 4; ++s) {
            const int k0 = kbase + s * 32;
            const float4 a0 = *reinterpret_cast<const float4*>(xrow + k0);
            const float4 a1 = *reinterpret_cast<const float4*>(xrow + k0 + 4);
            const float av[8] = { a0.x, a0.y, a0.z, a0.w, a1.x, a1.y, a1.z, a1.w };
            short8 ah, al;
#pragma unroll
            for (int j = 0; j < 8; ++j) {
                const unsigned short hi = f2bf(av[j]);
                ah[j] = (short)hi;
                al[j] = (short)f2bf(av[j] - bf2f(hi));
                nzflag |= (av[j] != 0.0f);
            }
            const int kloc = s * 32 + g * 8;
#pragma unroll
            for (int nf = 0; nf < 8; ++nf) {
                const int ub = (nf * 16 + l15) * LDK + kloc;
                const short8 bh = *reinterpret_cast<const short8*>(&wh[ub]);
                const short8 bl = *reinterpret_cast<const short8*>(&wl[ub]);
                acc[nf] = __builtin_amdgcn_mfma_f32_16x16x32_bf16(ah, bh, acc[nf], 0, 0, 0);
                acc[nf] = __builtin_amdgcn_mfma_f32_16x16x32_bf16(ah, bl, acc[nf], 0, 0, 0);
                acc[nf] = __builtin_amdgcn_mfma_f32_16x16x32_bf16(al, bh, acc[nf], 0, 0, 0);
            }
        }
        __syncthreads();
    }

    // frame f nonzero iff any ballot bit in {f, f+16, f+32, f+48}
    const unsigned long long nzb = __ballot(nzflag);

    // epilogue constants for this lane's 8 u-columns
    float b1v[8], w2v[8];
#pragma unroll
    for (int nf = 0; nf < 8; ++nf) {
        const int u = nf * 16 + l15;
        b1v[nf] = b1[u];
        w2v[nf] = W2[u];
    }
    const float bias2 = b2[0];

    // C/D layout (HW-verified): col = lane&15, row = (lane>>4)*4 + reg.
#pragma unroll
    for (int r = 0; r < 4; ++r) {
        float s = 0.0f;
#pragma unroll
        for (int nf = 0; nf < 8; ++nf) {
            float h = acc[nf][r] + b1v[nf];
            h = h > 0.0f ? h : 0.0f;
            s += h * w2v[nf];
        }
        s += __shfl_xor(s, 1);
        s += __shfl_xor(s, 2);
        s += __shfl_xor(s, 4);
        s += __shfl_xor(s, 8);
        if (l15 == 0) {
            const int fr = g * 4 + r;            // frame within wave's 16
            const bool nz = (nzb & (0x0001000100010001ULL << fr)) != 0ULL;
            scores[m0 + fr] = nz ? (s + bias2) : NEG_BIG;
        }
    }
}

// ---------------------------------------------------------------------------
// Pass 2: per batch row, sel[t] = 1 iff frame t in top-k (stable rank-by-
// count, matching lax.top_k's lower-index-first tie handling).
// ---------------------------------------------------------------------------
__global__ __launch_bounds__(256) void topk_kernel(
    const float* __restrict__ scores,  // [B*T]
    const int* __restrict__ kp,        // [1]
    int* __restrict__ sel)             // [B*T]
{
    __shared__ float srow[T];

    const int b     = blockIdx.x >> 3;   // 8 chunks of 256 frames per row
    const int chunk = blockIdx.x & 7;
    const float* row = scores + (size_t)b * T;

    for (int i = threadIdx.x; i < T / 4; i += 256)
        reinterpret_cast<float4*>(srow)[i] =
            reinterpret_cast<const float4*>(row)[i];
    __syncthreads();

    const int t   = chunk * 256 + threadIdx.x;
    const float s = srow[t];
    int cnt = 0;
    for (int i = 0; i < T / 4; ++i) {
        const float4 v = reinterpret_cast<const float4*>(srow)[i];
        const int base = i * 4;
        cnt += (v.x > s) || (v.x == s && (base + 0) < t);
        cnt += (v.y > s) || (v.y == s && (base + 1) < t);
        cnt += (v.z > s) || (v.z == s && (base + 2) < t);
        cnt += (v.w > s) || (v.w == s && (base + 3) < t);
    }
    sel[(size_t)b * T + t] = (cnt < kp[0]) ? 1 : 0;
}

// ---------------------------------------------------------------------------
// Pass 3: out[m,:] = sel[m] ? x[m,:] : 0.
// One block per 32 frames (2048 blocks -> 8 blocks/CU). Non-temporal stores
// (output never re-read): stream at fill rate, don't evict x from L3.
// ---------------------------------------------------------------------------
__global__ __launch_bounds__(256) void out_kernel(
    const float* __restrict__ x,
    const int* __restrict__ sel,
    float* __restrict__ out)
{
    __shared__ int ssel[32];

    const int fbase = blockIdx.x * 32;
    if (threadIdx.x < 32) ssel[threadIdx.x] = sel[fbase + threadIdx.x];
    __syncthreads();

    const size_t base4 = (size_t)fbase * (F / 4);
    const f32x4* x4 = reinterpret_cast<const f32x4*>(x) + base4;
    f32x4*       o4 = reinterpret_cast<f32x4*>(out) + base4;
    const f32x4 z = {0.0f, 0.0f, 0.0f, 0.0f};

#pragma unroll
    for (int it = 0; it < 16; ++it) {
        const int q  = it * 256 + threadIdx.x;
        const int fr = q >> 7;               // frame within 32 (F/4 = 128)
        f32x4 v = z;
        if (ssel[fr]) v = x4[q];
        __builtin_nontemporal_store(v, &o4[q]);
    }
}

// ---------------------------------------------------------------------------
extern "C" void kernel_launch(void* const* d_in, const int* in_sizes, int n_in,
                              void* d_out, int out_size, void* d_ws, size_t ws_size,
                              hipStream_t stream)
{
    const float* x  = (const float*)d_in[0];
    const float* W1 = (const float*)d_in[1];
    const float* b1 = (const float*)d_in[2];
    const float* W2 = (const float*)d_in[3];
    const float* b2 = (const float*)d_in[4];
    const int*   kp = (const int*)d_in[5];

    char* ws = (char*)d_ws;
    unsigned short* WThi = (unsigned short*)ws;               // 131072 B
    unsigned short* WTlo = (unsigned short*)(ws + 131072);    // 131072 B
    float* scores        = (float*)(ws + 262144);             // 262144 B
    int*   sel           = (int*)(ws + 524288);               // 262144 B

    float* out = (float*)d_out;

    prep_w<<<256, 256, 0, stream>>>(W1, WThi, WTlo);
    score_kernel<<<(B * T) / 128, 512, 0, stream>>>(x, WThi, WTlo, b1, W2, b2, scores);
    topk_kernel<<<B * 8, 256, 0, stream>>>(scores, kp, sel);
    out_kernel<<<(B * T) / 32, 256, 0, stream>>>(x, sel, out);
}